// Round 1
// baseline (348.685 us; speedup 1.0000x reference)
//
#include <hip/hip_runtime.h>
#include <math.h>

// Problem constants (from reference)
#define PN 32
#define PM 100
#define PK 500
#define PE 50

static constexpr float DEG2RAD = 0.017453292519943295f; // pi/180
static constexpr float TWO_R   = 2.0f * 6371.0f;

// out[n,m,k,e] = C[n,m,e] + ds[n,m,k] * D[n,m,e]
//   C[e] = esl[i][e] + (etl[i][e]*(500-dt) + etu[i][e]*dt) / 500
//   D[e] = (esu[i][e] - esl[i][e]) / 1000
//   i = (m < traj_len[n]) ? 1 : 0, dt = vec[n,m]
//   ds = 2*R*asin(sqrt(clip(hav,0,1)))
//
// Restructured streaming: thread tid<250 owns a FIXED e-pair p=tid%25
// (e = 2p,2p+1) so C/D live in 4 registers; k strides by 10 from
// k0=tid/25. Inner loop = 1 broadcast LDS read + 2 fmaf + 1 float2
// store (addr = base + 8*tid -> fully coalesced 512B/wave-instr).
// No per-element division, no divergent e-wrap branches, no per-element
// LDS reads of C/D.
__global__ __launch_bounds__(256) void embed_kernel(
    const int*   __restrict__ traj_loc,  // N*M
    const float* __restrict__ poi,       // LOC*2
    const float* __restrict__ vec,       // N*M
    const int*   __restrict__ traj_len,  // N
    const int*   __restrict__ cand,      // N*K
    const float* __restrict__ emb_su,    // 2*E
    const float* __restrict__ emb_sl,    // 2*E
    const float* __restrict__ emb_tu,    // 2*E
    const float* __restrict__ emb_tl,    // 2*E
    float*       __restrict__ out)       // N*M*K*E
{
    const int nm  = blockIdx.x;        // 0 .. N*M-1
    const int n   = nm / PM;
    const int m   = nm - n * PM;
    const int tid = threadIdx.x;

    __shared__ float s_ds[PK];

    // --- per-(n,m) uniform values (scalar loads: addresses tid-independent)
    const int   tl   = traj_loc[nm];
    const float lat1 = poi[2 * tl]     * DEG2RAD;
    const float lon1 = poi[2 * tl + 1] * DEG2RAD;
    const float coslat1 = __cosf(lat1);

    // --- stage ds[k]: haversine distance traj(n,m) -> cand(n,k)
    for (int k = tid; k < PK; k += 256) {
        const int   cl   = cand[n * PK + k];
        const float lat2 = poi[2 * cl]     * DEG2RAD;
        const float lon2 = poi[2 * cl + 1] * DEG2RAD;
        const float sdlat = __sinf(0.5f * (lat2 - lat1));
        const float sdlon = __sinf(0.5f * (lon2 - lon1));
        float a = sdlat * sdlat + coslat1 * __cosf(lat2) * (sdlon * sdlon);
        a = fminf(fmaxf(a, 0.0f), 1.0f);
        s_ds[k] = TWO_R * asinf(sqrtf(a));
    }

    __syncthreads();

    if (tid >= 250) return;           // 250 threads cover 10 rows x 25 pairs

    const int p  = tid % 25;          // e-pair index: e = {2p, 2p+1}, FIXED
    const int k0 = tid / 25;          // starting row 0..9, k strides by 10

    const int   i  = (m < traj_len[n]) ? 1 : 0;
    const float dt = vec[nm];

    // emb tables are 2x50 floats, L1-hot; float2 loads are 8B-aligned (e even)
    const float2 esl = reinterpret_cast<const float2*>(emb_sl)[i * 25 + p];
    const float2 esu = reinterpret_cast<const float2*>(emb_su)[i * 25 + p];
    const float2 etl = reinterpret_cast<const float2*>(emb_tl)[i * 25 + p];
    const float2 etu = reinterpret_cast<const float2*>(emb_tu)[i * 25 + p];

    const float C0 = esl.x + (etl.x * (500.0f - dt) + etu.x * dt) * (1.0f / 500.0f);
    const float C1 = esl.y + (etl.y * (500.0f - dt) + etu.y * dt) * (1.0f / 500.0f);
    const float D0 = (esu.x - esl.x) * (1.0f / 1000.0f);
    const float D1 = (esu.y - esl.y) * (1.0f / 1000.0f);

    // float2 index within this (n,m) tile: k*25 + p; per-iteration stride
    // is 10 rows = 250 float2 = 2000 B (stays perfectly coalesced).
    float2* __restrict__ out2 =
        reinterpret_cast<float2*>(out + (size_t)nm * (PK * PE)) + (k0 * 25 + p);

    #pragma unroll 10
    for (int it = 0; it < 50; ++it) {
        const float ds = s_ds[k0 + it * 10];   // 25 lanes share addr -> broadcast
        float2 v;
        v.x = fmaf(ds, D0, C0);
        v.y = fmaf(ds, D1, C1);
        out2[it * 250] = v;
    }
}

extern "C" void kernel_launch(void* const* d_in, const int* in_sizes, int n_in,
                              void* d_out, int out_size, void* d_ws, size_t ws_size,
                              hipStream_t stream) {
    const int*   traj_loc = (const int*)  d_in[0];
    const float* poi      = (const float*)d_in[1];
    const float* vec      = (const float*)d_in[2];
    const int*   traj_len = (const int*)  d_in[3];
    const int*   cand     = (const int*)  d_in[4];
    const float* emb_su   = (const float*)d_in[5];
    const float* emb_sl   = (const float*)d_in[6];
    const float* emb_tu   = (const float*)d_in[7];
    const float* emb_tl   = (const float*)d_in[8];
    float* out = (float*)d_out;

    dim3 grid(PN * PM);   // 3200 blocks, one per (n,m)
    dim3 block(256);
    embed_kernel<<<grid, block, 0, stream>>>(
        traj_loc, poi, vec, traj_len, cand,
        emb_su, emb_sl, emb_tu, emb_tl, out);
}